// Round 4
// 453.572 us; speedup vs baseline: 1.0614x; 1.0614x over previous
//
#include <hip/hip_runtime.h>
#include <hip/hip_bf16.h>

#define BB 16
#define LQ 1025
#define FF 768
#define HH 12
#define DD 64
#define EPSF 1e-8f

#define TPSTRIDE 6400     // per-head mask table: [0,64)=0, [64,4160)=|tp|, [4160,6400)=1
#define QPART_CLS 6270    // CLS-query qpart -> all reads land in the ones band
#define VSTRIDE 1040      // vtbuf key stride (16B aligned, >=1025, zero-padded)

#define LDK 72            // LDS tile row stride (u16): 144B, breaks 128B-stride conflicts

typedef unsigned short u16;
typedef __attribute__((ext_vector_type(8))) short  bf16x8;
typedef __attribute__((ext_vector_type(4))) float  f32x4;

__device__ __forceinline__ float bf2f(u16 u) {
    union { unsigned int i; float f; } c;
    c.i = ((unsigned int)u) << 16;
    return c.f;
}

__device__ __forceinline__ u16 f2bf(float f) {
    union { float f; unsigned int i; } c;
    c.f = f;
    unsigned int x = c.i;
    unsigned int r = (x + 0x7fffu + ((x >> 16) & 1u)) >> 16;  // round-nearest-even
    return (u16)r;
}

// ---------------------------------------------------------------------------
// Pre-pass A: convert x (fp32) -> xb (bf16).
// ---------------------------------------------------------------------------
__global__ __launch_bounds__(256) void convert_x(
    const float* __restrict__ x, u16* __restrict__ xb, int n4)
{
    int i = blockIdx.x * blockDim.x + threadIdx.x;
    const int stride = gridDim.x * blockDim.x;
    for (; i < n4; i += stride) {
        float4 f = ((const float4*)x)[i];
        ushort4 o;
        o.x = f2bf(f.x); o.y = f2bf(f.y); o.z = f2bf(f.z); o.w = f2bf(f.w);
        ((ushort4*)xb)[i] = o;
    }
}

// ---------------------------------------------------------------------------
// Pre-pass B: transpose+convert the four 768x768 weight matrices to bf16.
// ---------------------------------------------------------------------------
__global__ __launch_bounds__(256) void transpose_w(
    const float* __restrict__ wq, const float* __restrict__ wk,
    const float* __restrict__ wv, const float* __restrict__ wo,
    u16* __restrict__ wqt, u16* __restrict__ wkt,
    u16* __restrict__ wvt, u16* __restrict__ wot)
{
    const int z = blockIdx.z;
    const float* __restrict__ src = (z == 0) ? wq : (z == 1) ? wk : (z == 2) ? wv : wo;
    u16* __restrict__ dst         = (z == 0) ? wqt : (z == 1) ? wkt : (z == 2) ? wvt : wot;

    const int c0 = blockIdx.x * 64;
    const int r0 = blockIdx.y * 64;

    __shared__ u16 tile[64][72];

    const int t   = threadIdx.x;
    const int row = t >> 2;
    const int cs  = (t & 3) << 4;

    {
        const float* p = src + (size_t)(r0 + row) * 768 + c0 + cs;
#pragma unroll
        for (int q = 0; q < 4; ++q) {
            float4 f = *(const float4*)(p + 4 * q);
            ushort4 o;
            o.x = f2bf(f.x); o.y = f2bf(f.y); o.z = f2bf(f.z); o.w = f2bf(f.w);
            *(ushort4*)&tile[row][cs + 4 * q] = o;
        }
    }
    __syncthreads();
    {
        u16* p = dst + (size_t)(c0 + row) * 768 + r0 + cs;
#pragma unroll
        for (int q = 0; q < 4; ++q) {
            ushort4 o;
            o.x = tile[cs + 4 * q + 0][row];
            o.y = tile[cs + 4 * q + 1][row];
            o.z = tile[cs + 4 * q + 2][row];
            o.w = tile[cs + 4 * q + 3][row];
            *(ushort4*)(p + 4 * q) = o;
        }
    }
}

// ---------------------------------------------------------------------------
// Pre-pass C: mask table tpa[h][TPSTRIDE] ([0,64)=0, mid=|tp|, tail=1).
// ---------------------------------------------------------------------------
__global__ __launch_bounds__(256) void build_tpa(
    const float* __restrict__ tp, float* __restrict__ tpa)
{
    int i = blockIdx.x * 256 + threadIdx.x;
    if (i >= HH * TPSTRIDE) return;
    int h = i / TPSTRIDE, j = i - h * TPSTRIDE;
    float v;
    if (j < 64) v = 0.f;
    else if (j < 64 + 4096) v = fabsf(tp[h * 4096 + (j - 64)]);
    else v = 1.f;
    tpa[i] = v;
}

// ---------------------------------------------------------------------------
// Pre-pass C2: pack biases [bq|bk|bv] -> bias_cat[2304].
// ---------------------------------------------------------------------------
__global__ __launch_bounds__(256) void pack_bias(
    const float* __restrict__ bq, const float* __restrict__ bk,
    const float* __restrict__ bv, float* __restrict__ bias_cat)
{
    int i = blockIdx.x * 256 + threadIdx.x;
    if (i >= 2304) return;
    float v = (i < 768) ? bq[i] : (i < 1536) ? bk[i - 768] : bv[i - 1536];
    bias_cat[i] = v;
}

// ---------------------------------------------------------------------------
// Pre-pass D: transpose V per (b,h): vbuf [bh][l][d] -> vtbuf [bh][d][VSTRIDE].
// ---------------------------------------------------------------------------
__global__ __launch_bounds__(256) void transpose_v(
    const u16* __restrict__ vbuf, u16* __restrict__ vtbuf)
{
    const int bh = blockIdx.y;
    const int lt = blockIdx.x;           // 0..16
    __shared__ u16 tile[64][65];
    const int t   = threadIdx.x;
    const int row = t >> 2;              // 0..63
    const int seg = (t & 3) << 4;        // 0,16,32,48

    {
        int l = lt * 64 + row;
        if (l < LQ) {
            const ushort4* p = (const ushort4*)(vbuf + ((size_t)bh * LQ + l) * 64 + seg);
#pragma unroll
            for (int q = 0; q < 4; ++q) {
                ushort4 a = p[q];
                tile[row][seg + 4 * q + 0] = a.x;
                tile[row][seg + 4 * q + 1] = a.y;
                tile[row][seg + 4 * q + 2] = a.z;
                tile[row][seg + 4 * q + 3] = a.w;
            }
        } else {
#pragma unroll
            for (int j = 0; j < 16; ++j) tile[row][seg + j] = 0;
        }
    }
    __syncthreads();
    {
        int kbase = lt * 64 + seg;
        if (kbase + 16 <= VSTRIDE) {
            u16* q = vtbuf + (size_t)bh * 64 * VSTRIDE + (size_t)row * VSTRIDE + kbase;
#pragma unroll
            for (int g = 0; g < 4; ++g) {
                ushort4 o;
                o.x = tile[seg + 4 * g + 0][row];
                o.y = tile[seg + 4 * g + 1][row];
                o.z = tile[seg + 4 * g + 2][row];
                o.w = tile[seg + 4 * g + 3][row];
                *(ushort4*)(q + 4 * g) = o;
            }
        }
    }
}

// ---------------------------------------------------------------------------
// Kernel 1: merged QKV projection on MFMA.
//   BK=64, REGISTER-staged (uint4 loads + ds_write_b128 — no global_load_lds),
//   LDS [128][LDK=72] padded (144B stride: write & read bank-conflict-free
//   class). 2 barriers per K-step, 12 K-steps. Tile 128x128, 64x64/wave.
//   Per-acc accumulation order identical to the BK=32 version (ascending k,
//   32-wide MFMA windows) -> bit-identical output.
// ---------------------------------------------------------------------------
__global__ __launch_bounds__(256) void gemm_qkv_mfma(
    const u16* __restrict__ xb, const u16* __restrict__ wt,
    const float* __restrict__ bias_cat,
    u16* __restrict__ qbuf, u16* __restrict__ kbuf, u16* __restrict__ vbuf)
{
    const int M   = BB * LQ;
    const int m0  = blockIdx.x * 128;
    const int n0g = blockIdx.y * 128;          // global n in [0,2304)

    __shared__ u16 As[128 * LDK];
    __shared__ u16 Bs[128 * LDK];

    const int t    = threadIdx.x;
    const int wave = t >> 6;
    const int lane = t & 63;
    const int quad = lane >> 4;
    const int l16  = lane & 15;
    const int wm   = (wave >> 1) << 6;         // 0,64
    const int wn   = (wave & 1) << 6;          // 0,64

    const int sm   = t >> 1;                   // staging row 0..127
    const int sc   = (t & 1) << 5;             // staging col 0,32 (u16)

    const bool avalid = (m0 + sm) < M;
    const u16* pa = xb + (size_t)(m0 + sm) * 768 + sc;
    const u16* pb = wt + (size_t)(n0g + sm) * 768 + sc;

    f32x4 acc[4][4];
#pragma unroll
    for (int i = 0; i < 4; ++i)
#pragma unroll
        for (int j = 0; j < 4; ++j)
            acc[i][j] = (f32x4){0.f, 0.f, 0.f, 0.f};

    for (int k0 = 0; k0 < 768; k0 += 64) {
        __syncthreads();
        if (avalid) {
            const uint4* p = (const uint4*)(pa + k0);
#pragma unroll
            for (int q = 0; q < 4; ++q)
                *(uint4*)&As[sm * LDK + sc + 8 * q] = p[q];
        } else {
            uint4 z; z.x = 0; z.y = 0; z.z = 0; z.w = 0;
#pragma unroll
            for (int q = 0; q < 4; ++q)
                *(uint4*)&As[sm * LDK + sc + 8 * q] = z;
        }
        {
            const uint4* p = (const uint4*)(pb + k0);
#pragma unroll
            for (int q = 0; q < 4; ++q)
                *(uint4*)&Bs[sm * LDK + sc + 8 * q] = p[q];
        }
        __syncthreads();

#pragma unroll
        for (int h2 = 0; h2 < 2; ++h2) {
            bf16x8 af[4], bf[4];
#pragma unroll
            for (int i = 0; i < 4; ++i)
                af[i] = *(const bf16x8*)&As[(wm + 16 * i + l16) * LDK + h2 * 32 + quad * 8];
#pragma unroll
            for (int j = 0; j < 4; ++j)
                bf[j] = *(const bf16x8*)&Bs[(wn + 16 * j + l16) * LDK + h2 * 32 + quad * 8];
#pragma unroll
            for (int i = 0; i < 4; ++i)
#pragma unroll
                for (int j = 0; j < 4; ++j)
                    acc[i][j] = __builtin_amdgcn_mfma_f32_16x16x32_bf16(af[i], bf[j], acc[i][j], 0, 0, 0);
        }
    }

    // epilogue (type block-uniform)
    const int type = (n0g >= 1536) ? 2 : (n0g >= 768) ? 1 : 0;
    u16* __restrict__ outb = (type == 0) ? qbuf : (type == 1) ? kbuf : vbuf;
    const int nbase = n0g - type * 768;

#pragma unroll
    for (int i = 0; i < 4; ++i) {
#pragma unroll
        for (int reg = 0; reg < 4; ++reg) {
            int gm = m0 + wm + 16 * i + quad * 4 + reg;
            if (gm >= M) continue;
            int b_idx = gm / LQ;
            int l     = gm - b_idx * LQ;
#pragma unroll
            for (int j = 0; j < 4; ++j) {
                int nloc = nbase + wn + 16 * j + l16;   // 0..767 within matrix
                int h = nloc >> 6, d = nloc & 63;
                float v = acc[i][j][reg] + bias_cat[n0g + wn + 16 * j + l16];
                if (type == 0) v = fmaxf(v * 0.125f, 0.f) + EPSF;
                else if (type == 1) v = fmaxf(v, 0.f) + EPSF;
                outb[((size_t)(b_idx * HH + h) * LQ + l) * 64 + d] = f2bf(v);
            }
        }
    }
}

// ---------------------------------------------------------------------------
// Kernel 2: fused attention, v4 (round-0 exact) — double-buffered K/V,
//   1 barrier per k-tile, S^T = K.Q^T MFMA, table-driven mask (idx ladder
//   -128/tile), register prefetch 2 tiles ahead, pre-transposed V.
// ---------------------------------------------------------------------------
__global__ __launch_bounds__(256) void attn_fused(
    const u16* __restrict__ qbuf, const u16* __restrict__ kbuf,
    const u16* __restrict__ vtbuf, const float* __restrict__ tpa,
    u16* __restrict__ obuf)
{
    const int bh = blockIdx.y;
    const int b  = bh / HH;
    const int h  = bh - b * HH;
    const int q0 = blockIdx.x * 64;

    __shared__ u16 SQ[64][72];        // Q tile, then S tile (wave-private rows)
    __shared__ u16 Ks[2][64][72];
    __shared__ u16 Vt[2][64][72];     // [d][key]

    const int t    = threadIdx.x;
    const int wave = t >> 6;
    const int lane = t & 63;
    const int quad = lane >> 4;
    const int l16  = lane & 15;
    const int w16  = wave << 4;

    const size_t base  = (size_t)bh * LQ * 64;
    const size_t vbase = (size_t)bh * 64 * VSTRIDE;
    const float* tb = tpa + h * TPSTRIDE;

    const int srow = t >> 2;          // staging row
    const int sseg = (t & 3) << 4;    // staging seg (u16)

    // ---- stage Q tile (overrun reads land in kbuf, harmless) ----
    {
        const uint4* qp = (const uint4*)(qbuf + base + (size_t)(q0 + srow) * 64 + sseg);
        *(uint4*)&SQ[srow][sseg]     = qp[0];
        *(uint4*)&SQ[srow][sseg + 8] = qp[1];
    }

    // ---- per-lane q metadata ----
    const int qi = q0 + w16 + l16;
    int qpart;
    if (qi == 0) qpart = QPART_CLS;
    else { int qm1 = qi - 1; qpart = (((qm1 >> 5) + 32) << 6) + (qm1 & 31) + 32; }

    int idx[16];
#pragma unroll
    for (int ct = 0; ct < 4; ++ct)
#pragma unroll
        for (int reg = 0; reg < 4; ++reg) {
            int km1 = ct * 16 + quad * 4 + reg - 1;
            idx[ct * 4 + reg] = 64 + qpart - (((km1 >> 5) << 6) + (km1 & 31));
        }

    // ---- prefetch tile 0 into registers ----
    uint4 kr0, kr1, vr0, vr1;
    {
        uint4 z; z.x = 0; z.y = 0; z.z = 0; z.w = 0;
        int ki = srow;
        if (ki < LQ) {
            const uint4* kp = (const uint4*)(kbuf + base + (size_t)ki * 64 + sseg);
            kr0 = kp[0]; kr1 = kp[1];
        } else { kr0 = z; kr1 = z; }
        const uint4* vp = (const uint4*)(vtbuf + vbase + (size_t)srow * VSTRIDE + sseg);
        vr0 = vp[0]; vr1 = vp[1];
    }

    __syncthreads();   // Q staged

    bf16x8 qf0 = *(const bf16x8*)&SQ[w16 + l16][quad * 8];
    bf16x8 qf1 = *(const bf16x8*)&SQ[w16 + l16][32 + quad * 8];

    // write tile 0 into buffer 0
    *(uint4*)&Ks[0][srow][sseg]     = kr0;
    *(uint4*)&Ks[0][srow][sseg + 8] = kr1;
    *(uint4*)&Vt[0][srow][sseg]     = vr0;
    *(uint4*)&Vt[0][srow][sseg + 8] = vr1;

    // prefetch tile 1
    {
        uint4 z; z.x = 0; z.y = 0; z.z = 0; z.w = 0;
        int ki = 64 + srow;
        if (ki < LQ) {
            const uint4* kp = (const uint4*)(kbuf + base + (size_t)ki * 64 + sseg);
            kr0 = kp[0]; kr1 = kp[1];
        } else { kr0 = z; kr1 = z; }
        int vcol = 64 + sseg;
        const uint4* vp = (const uint4*)(vtbuf + vbase + (size_t)srow * VSTRIDE + vcol);
        vr0 = vp[0]; vr1 = vp[1];
    }

    f32x4 acc_o[4];
#pragma unroll
    for (int dt = 0; dt < 4; ++dt) acc_o[dt] = (f32x4){0.f, 0.f, 0.f, 0.f};
    float den = 0.f;

    __syncthreads();   // buffer 0 visible

    for (int kt = 0; kt < 17; ++kt) {
        const int p = kt & 1;

        // write prefetched tile kt+1 into the idle buffer
        if (kt < 16) {
            *(uint4*)&Ks[p ^ 1][srow][sseg]     = kr0;
            *(uint4*)&Ks[p ^ 1][srow][sseg + 8] = kr1;
            *(uint4*)&Vt[p ^ 1][srow][sseg]     = vr0;
            *(uint4*)&Vt[p ^ 1][srow][sseg + 8] = vr1;
        }
        // prefetch tile kt+2
        if (kt < 15) {
            uint4 z; z.x = 0; z.y = 0; z.z = 0; z.w = 0;
            int k0n = (kt + 2) * 64;
            int ki = k0n + srow;
            if (ki < LQ) {
                const uint4* kp = (const uint4*)(kbuf + base + (size_t)ki * 64 + sseg);
                kr0 = kp[0]; kr1 = kp[1];
            } else { kr0 = z; kr1 = z; }
            int vcol = k0n + sseg;
            if (vcol + 16 <= VSTRIDE) {
                const uint4* vp = (const uint4*)(vtbuf + vbase + (size_t)srow * VSTRIDE + vcol);
                vr0 = vp[0]; vr1 = vp[1];
            } else { vr0 = z; vr1 = z; }
        }

        // tm gather (overlaps MFMAs)
        float tmv[16];
#pragma unroll
        for (int e = 0; e < 16; ++e) tmv[e] = tb[idx[e]];

        // ---- QK^T as S^T = K.Q^T from buffer p ----
        f32x4 acc_s[4];
#pragma unroll
        for (int ct = 0; ct < 4; ++ct) {
            bf16x8 kf0 = *(const bf16x8*)&Ks[p][ct * 16 + l16][quad * 8];
            bf16x8 kf1 = *(const bf16x8*)&Ks[p][ct * 16 + l16][32 + quad * 8];
            f32x4 z = (f32x4){0.f, 0.f, 0.f, 0.f};
            z = __builtin_amdgcn_mfma_f32_16x16x32_bf16(kf0, qf0, z, 0, 0, 0);
            z = __builtin_amdgcn_mfma_f32_16x16x32_bf16(kf1, qf1, z, 0, 0, 0);
            acc_s[ct] = z;
        }

        if (kt == 0) { if (quad == 0) tmv[0] = 1.0f; }   // CLS key

        // ---- mask + eps + den + S write (wave-private rows) ----
#pragma unroll
        for (int ct = 0; ct < 4; ++ct) {
            float s0 = acc_s[ct][0] * tmv[ct * 4 + 0] + EPSF;
            float s1 = acc_s[ct][1] * tmv[ct * 4 + 1] + EPSF;
            float s2 = acc_s[ct][2] * tmv[ct * 4 + 2] + EPSF;
            float s3 = acc_s[ct][3] * tmv[ct * 4 + 3] + EPSF;
            den += (s0 + s1) + (s2 + s3);
            ushort4 w;
            w.x = f2bf(s0); w.y = f2bf(s1); w.z = f2bf(s2); w.w = f2bf(s3);
            *(ushort4*)&SQ[w16 + l16][ct * 16 + quad * 4] = w;
        }
#pragma unroll
        for (int e = 0; e < 16; ++e) idx[e] -= 128;

        // ---- PV: A = S (own rows, same-wave lgkmcnt), B = Vt[p] ----
        {
            bf16x8 a0 = *(const bf16x8*)&SQ[w16 + l16][quad * 8];
            bf16x8 a1 = *(const bf16x8*)&SQ[w16 + l16][32 + quad * 8];
#pragma unroll
            for (int dt = 0; dt < 4; ++dt) {
                bf16x8 b0 = *(const bf16x8*)&Vt[p][dt * 16 + l16][quad * 8];
                bf16x8 b1 = *(const bf16x8*)&Vt[p][dt * 16 + l16][32 + quad * 8];
                acc_o[dt] = __builtin_amdgcn_mfma_f32_16x16x32_bf16(a0, b0, acc_o[dt], 0, 0, 0);
                acc_o[dt] = __builtin_amdgcn_mfma_f32_16x16x32_bf16(a1, b1, acc_o[dt], 0, 0, 0);
            }
        }

        if (kt < 16) __syncthreads();   // staging visible, everyone done with buf p
    }

    // ---- den across quads ----
    den += __shfl_xor(den, 16);
    den += __shfl_xor(den, 32);
    float invd = 1.f / den;

#pragma unroll
    for (int reg = 0; reg < 4; ++reg) {
        int r = quad * 4 + reg;
        float iv = __shfl(invd, r, 64);
        int qrow = q0 + w16 + r;
        if (qrow < LQ) {
            u16* p = obuf + ((size_t)(b * LQ + qrow) * HH + h) * 64;
#pragma unroll
            for (int dt = 0; dt < 4; ++dt)
                p[dt * 16 + l16] = f2bf(acc_o[dt][reg] * iv);
        }
    }
}

// ---------------------------------------------------------------------------
// Kernel 3: output projection on MFMA — BK=64, register-staged, [128][72].
// ---------------------------------------------------------------------------
__global__ __launch_bounds__(256) void gemm_out_mfma(
    const u16* __restrict__ a, const u16* __restrict__ wot,
    const float* __restrict__ bo, float* __restrict__ out)
{
    const int M  = BB * LQ;
    const int m0 = blockIdx.x * 128;
    const int n0 = blockIdx.y * 128;

    __shared__ u16 As[128 * LDK];
    __shared__ u16 Bs[128 * LDK];

    const int t    = threadIdx.x;
    const int wave = t >> 6;
    const int lane = t & 63;
    const int quad = lane >> 4;
    const int l16  = lane & 15;
    const int wm   = (wave >> 1) << 6;
    const int wn   = (wave & 1) << 6;

    const int sm   = t >> 1;
    const int sc   = (t & 1) << 5;

    const bool avalid = (m0 + sm) < M;
    const u16* pa = a   + (size_t)(m0 + sm) * 768 + sc;
    const u16* pb = wot + (size_t)(n0 + sm) * 768 + sc;

    f32x4 acc[4][4];
#pragma unroll
    for (int i = 0; i < 4; ++i)
#pragma unroll
        for (int j = 0; j < 4; ++j)
            acc[i][j] = (f32x4){0.f, 0.f, 0.f, 0.f};

    for (int k0 = 0; k0 < 768; k0 += 64) {
        __syncthreads();
        if (avalid) {
            const uint4* p = (const uint4*)(pa + k0);
#pragma unroll
            for (int q = 0; q < 4; ++q)
                *(uint4*)&As[sm * LDK + sc + 8 * q] = p[q];
        } else {
            uint4 z; z.x = 0; z.y = 0; z.z = 0; z.w = 0;
#pragma unroll
            for (int q = 0; q < 4; ++q)
                *(uint4*)&As[sm * LDK + sc + 8 * q] = z;
        }
        {
            const uint4* p = (const uint4*)(pb + k0);
#pragma unroll
            for (int q = 0; q < 4; ++q)
                *(uint4*)&Bs[sm * LDK + sc + 8 * q] = p[q];
        }
        __syncthreads();

#pragma unroll
        for (int h2 = 0; h2 < 2; ++h2) {
            bf16x8 af[4], bf[4];
#pragma unroll
            for (int i = 0; i < 4; ++i)
                af[i] = *(const bf16x8*)&As[(wm + 16 * i + l16) * LDK + h2 * 32 + quad * 8];
#pragma unroll
            for (int j = 0; j < 4; ++j)
                bf[j] = *(const bf16x8*)&Bs[(wn + 16 * j + l16) * LDK + h2 * 32 + quad * 8];
#pragma unroll
            for (int i = 0; i < 4; ++i)
#pragma unroll
                for (int j = 0; j < 4; ++j)
                    acc[i][j] = __builtin_amdgcn_mfma_f32_16x16x32_bf16(af[i], bf[j], acc[i][j], 0, 0, 0);
        }
    }

#pragma unroll
    for (int i = 0; i < 4; ++i) {
#pragma unroll
        for (int reg = 0; reg < 4; ++reg) {
            int gm = m0 + wm + 16 * i + quad * 4 + reg;
            if (gm >= M) continue;
            float* p = out + (size_t)gm * 768;
#pragma unroll
            for (int j = 0; j < 4; ++j) {
                int n = n0 + wn + 16 * j + l16;
                p[n] = acc[i][j][reg] + bo[n];
            }
        }
    }
}

extern "C" void kernel_launch(void* const* d_in, const int* in_sizes, int n_in,
                              void* d_out, int out_size, void* d_ws, size_t ws_size,
                              hipStream_t stream) {
    const float* x  = (const float*)d_in[0];
    const float* wq = (const float*)d_in[1];
    const float* bq = (const float*)d_in[2];
    const float* wk = (const float*)d_in[3];
    const float* bk = (const float*)d_in[4];
    const float* wv = (const float*)d_in[5];
    const float* bv = (const float*)d_in[6];
    const float* wo = (const float*)d_in[7];
    const float* bo = (const float*)d_in[8];
    const float* tp = (const float*)d_in[9];
    float* out = (float*)d_out;

    const size_t per = (size_t)BB * HH * LQ * DD;  // 12,595,200 elements
    const size_t wsz = (size_t)FF * FF;            // 589,824 elements
    u16* ws16  = (u16*)d_ws;
    u16* qbuf  = ws16;
    u16* kbuf  = qbuf + per;
    u16* vbuf  = kbuf + per;          // V from QKV GEMM; reused as obuf in attn
    u16* xb    = vbuf + per;          // x bf16; reused as vtbuf after gemm_qkv
    u16* wqt   = xb + per;            // wqt|wkt|wvt contiguous = merged wt
    u16* wkt   = wqt + wsz;
    u16* wvt   = wkt + wsz;
    u16* wot   = wvt + wsz;           // survives until gemm_out
    float* tpa = (float*)(wot + wsz); // 12*TPSTRIDE floats
    float* bias_cat = tpa + HH * TPSTRIDE;  // 2304 floats

    u16* vtbuf = xb;                  // 192*64*VSTRIDE spills into dead wqt region
    u16* obuf  = vbuf;

    convert_x<<<2048, 256, 0, stream>>>(x, xb, (int)(per / 4));
    dim3 gt(12, 12, 4);
    transpose_w<<<gt, 256, 0, stream>>>(wq, wk, wv, wo, wqt, wkt, wvt, wot);
    build_tpa<<<(HH * TPSTRIDE + 255) / 256, 256, 0, stream>>>(tp, tpa);
    pack_bias<<<9, 256, 0, stream>>>(bq, bk, bv, bias_cat);

    dim3 g1(129, 18);
    gemm_qkv_mfma<<<g1, 256, 0, stream>>>(xb, wqt, bias_cat, qbuf, kbuf, vbuf);

    dim3 gv(17, BB * HH);
    transpose_v<<<gv, 256, 0, stream>>>(vbuf, vtbuf);

    dim3 g2(17, BB * HH);
    attn_fused<<<g2, 256, 0, stream>>>(qbuf, kbuf, vtbuf, tpa, obuf);

    dim3 g3(129, 6);
    gemm_out_mfma<<<g3, 256, 0, stream>>>(obuf, wot, bo, out);
}